// Round 1
// baseline (404.754 us; speedup 1.0000x reference)
//
#include <hip/hip_runtime.h>
#include <hip/hip_bf16.h>
#include <math.h>

// Problem constants (from reference setup_inputs)
#define BB   32
#define TT_  8192
#define QD   512
#define VD   256
#define DD   128
#define TINYF 1.17549435e-38f

// Tiling for the score kernel
#define TTILE 64   // t rows per block
#define CCH   32   // c-chunk

// Speculation window: scores computed eagerly for t < TSPEC; beyond that only
// if the exclusive cumprod has not underflowed to 0 (checked dynamically).
#define TSPEC_CHUNKS 2           // chunks of 256 -> t < 512
#define TSPEC (TSPEC_CHUNKS*256)
#define TSPEC_TILES (TSPEC/TTILE)

// ---------------- Kernel 1: q = query @ Wq + bq ----------------
__global__ __launch_bounds__(128) void k_qproj(
    const float* __restrict__ query, const float* __restrict__ Wq,
    const float* __restrict__ bq, float* __restrict__ qout) {
  int b = blockIdx.x, d = threadIdx.x;
  __shared__ float qrow[QD];
  for (int c = threadIdx.x; c < QD; c += 128) qrow[c] = query[b*QD + c];
  __syncthreads();
  float acc = bq[d];
  #pragma unroll 8
  for (int c = 0; c < QD; ++c) acc = fmaf(qrow[c], Wq[c*DD + d], acc);
  qout[b*DD + d] = acc;
}

// ---------------- Kernel 2: scores for a t-range ----------------
// score[b][t] = sum_d attv[d]*tanh(q[b][d] + (value[b][t]@Wv)[d] + bv[d]) + sbias
// grid: (num_t_tiles, B); flags!=null -> early-exit when flags[b]==0.
__global__ __launch_bounds__(256) void k_score(
    const float* __restrict__ value, const float* __restrict__ Wv,
    const float* __restrict__ bv, const float* __restrict__ qv,
    const float* __restrict__ attv, const float* __restrict__ sbias,
    float* __restrict__ score, int t_tile_base, const int* __restrict__ flags) {
  int b = blockIdx.y;
  if (flags && flags[b] == 0) return;
  int t0 = (t_tile_base + blockIdx.x) * TTILE;
  int tid = threadIdx.x;
  int dq = tid & 31;   // d-group of 4: d = dq*4..dq*4+3
  int tq = tid >> 5;   // t-group of 8: t = t0 + tq*8 .. +7

  __shared__ float WvL[CCH * DD];        // 16 KB
  __shared__ float valT[CCH * 68];       // transposed value tile, stride 68 (8.7 KB)

  float acc[8][4];
  #pragma unroll
  for (int i = 0; i < 8; ++i)
    #pragma unroll
    for (int j = 0; j < 4; ++j) acc[i][j] = 0.f;

  const float* vbase = value + ((size_t)b * TT_ + t0) * VD;

  for (int c0 = 0; c0 < VD; c0 += CCH) {
    // stage Wv chunk [CCH][128]
    const float4* wsrc = (const float4*)(Wv + (size_t)c0 * DD);
    float4* wdst = (float4*)WvL;
    #pragma unroll
    for (int k = 0; k < 4; ++k) wdst[tid + 256 * k] = wsrc[tid + 256 * k];
    // stage value chunk transposed: valT[cc][tt]
    #pragma unroll
    for (int k = 0; k < 2; ++k) {
      int id = tid * 2 + k;            // 0..511
      int tt = id >> 3;                // 0..63
      int c4 = id & 7;                 // float4 within row
      float4 vv = *(const float4*)(vbase + (size_t)tt * VD + c0 + c4 * 4);
      int cr = c4 * 4;
      valT[(cr + 0) * 68 + tt] = vv.x;
      valT[(cr + 1) * 68 + tt] = vv.y;
      valT[(cr + 2) * 68 + tt] = vv.z;
      valT[(cr + 3) * 68 + tt] = vv.w;
    }
    __syncthreads();
    #pragma unroll 4
    for (int cc = 0; cc < CCH; ++cc) {
      const float4 wv  = *(const float4*)(&WvL[cc * DD + dq * 4]);
      const float4 va0 = *(const float4*)(&valT[cc * 68 + tq * 8]);
      const float4 va1 = *(const float4*)(&valT[cc * 68 + tq * 8 + 4]);
      float va[8] = {va0.x, va0.y, va0.z, va0.w, va1.x, va1.y, va1.z, va1.w};
      #pragma unroll
      for (int i = 0; i < 8; ++i) {
        acc[i][0] = fmaf(va[i], wv.x, acc[i][0]);
        acc[i][1] = fmaf(va[i], wv.y, acc[i][1]);
        acc[i][2] = fmaf(va[i], wv.z, acc[i][2]);
        acc[i][3] = fmaf(va[i], wv.w, acc[i][3]);
      }
    }
    __syncthreads();
  }

  // epilogue: tanh + attv dot + cross-lane reduce over the 32 dq lanes
  float sb = sbias[0];
  float qd[4], av[4], bvv[4];
  #pragma unroll
  for (int j = 0; j < 4; ++j) {
    int d = dq * 4 + j;
    qd[j]  = qv[b * DD + d];
    av[j]  = attv[d];
    bvv[j] = bv[d];
  }
  #pragma unroll
  for (int i = 0; i < 8; ++i) {
    float s = 0.f;
    #pragma unroll
    for (int j = 0; j < 4; ++j) {
      float x = qd[j] + acc[i][j] + bvv[j];
      s += av[j] * tanhf(x);
    }
    #pragma unroll
    for (int m = 16; m >= 1; m >>= 1) s += __shfl_xor(s, m, 64);
    if (dq == 0) score[(size_t)b * TT_ + t0 + tq * 8 + i] = s + sb;
  }
}

// ---------------- Kernel 3: monotonic-attention scan ----------------
// phase 0: chunks [0, nchunks); decides per-b whether cp underflowed (fast path:
//          zero-fill tail, flags[b]=0) or fallback needed (flags[b]=1, save carries).
// phase 1: continuation for flagged b only.
__global__ __launch_bounds__(256) void k_scan(
    const float* __restrict__ score, const float* __restrict__ prev,
    float* __restrict__ align_out, float* __restrict__ suma,
    float* __restrict__ carryLs, float* __restrict__ carryDs,
    int* __restrict__ flags, int chunk0, int nchunks, int phase) {
  int b = blockIdx.x, tid = threadIdx.x;
  int lane = tid & 63, w = tid >> 6;
  __shared__ float wsA[4], wsB[4];

  float cL, cD, sacc;
  if (phase == 1) {
    if (flags[b] == 0) return;
    cL = carryLs[b]; cD = carryDs[b]; sacc = suma[b];
  } else {
    cL = 0.f; cD = 0.f; sacc = 0.f;
  }

  const size_t base = (size_t)b * TT_;
  for (int ch = 0; ch < nchunks; ++ch) {
    int t = (chunk0 + ch) * 256 + tid;
    float s = score[base + t];
    float p  = 1.f / (1.f + expf(-s));      // sigmoid, safe for all s
    float om = 1.f / (1.f + expf(s));       // 1-p without cancellation
    float l = logf(fmaxf(om, TINYF));       // log(clip(1-p, TINY, 1))

    // inclusive block scan of l
    float inc = l;
    #pragma unroll
    for (int o = 1; o < 64; o <<= 1) {
      float n = __shfl_up(inc, o, 64);
      if (lane >= o) inc += n;
    }
    if (lane == 63) wsA[w] = inc;
    __syncthreads();
    float off = 0.f;
    #pragma unroll
    for (int j = 0; j < 4; ++j) if (j < w) off += wsA[j];
    float totA = wsA[0] + wsA[1] + wsA[2] + wsA[3];
    float cums = cL + off + inc;            // inclusive cumsum of logs
    float cp = expf(cums - l);              // exclusive cumprod of (1-p)
    float den = prev[base + t] / fminf(fmaxf(cp, 1e-10f), 1.f);

    // inclusive block scan of den
    float inc2 = den;
    #pragma unroll
    for (int o = 1; o < 64; o <<= 1) {
      float n = __shfl_up(inc2, o, 64);
      if (lane >= o) inc2 += n;
    }
    if (lane == 63) wsB[w] = inc2;
    __syncthreads();
    float off2 = 0.f;
    #pragma unroll
    for (int j = 0; j < 4; ++j) if (j < w) off2 += wsB[j];
    float totB = wsB[0] + wsB[1] + wsB[2] + wsB[3];

    float a = p * cp * (cD + off2 + inc2);
    align_out[base + t] = a;
    sacc += a;
    cL += totA; cD += totB;
    __syncthreads();
  }

  // block-reduce suma
  #pragma unroll
  for (int o = 32; o >= 1; o >>= 1) sacc += __shfl_xor(sacc, o, 64);
  if (lane == 0) wsA[w] = sacc;
  __syncthreads();
  float stot = wsA[0] + wsA[1] + wsA[2] + wsA[3];

  if (phase == 0) {
    bool done = (expf(cL) == 0.f);  // cp is 0 for ALL later t -> alignment all 0
    if (done) {
      int tstart = (chunk0 + nchunks) * 256;
      float4 z = make_float4(0.f, 0.f, 0.f, 0.f);
      float4* dst = (float4*)(align_out + base + tstart);
      int n4 = (TT_ - tstart) / 4;
      for (int i = tid; i < n4; i += 256) dst[i] = z;
      if (tid == 0) { flags[b] = 0; suma[b] = stot; }
    } else {
      if (tid == 0) { flags[b] = 1; suma[b] = stot; carryLs[b] = cL; carryDs[b] = cD; }
    }
  } else {
    if (tid == 0) suma[b] = stot;
  }
}

// ---------------- Kernel 4: u[b][c] = sum_t a[b][t] * value[b][t][c] ----------------
// per-chunk all-zero skip: only chunks with nonzero alignment read value.
__global__ __launch_bounds__(256) void k_u(
    const float* __restrict__ value, const float* __restrict__ align,
    float* __restrict__ u) {
  int b = blockIdx.y, chunk = blockIdx.x, c = threadIdx.x;
  __shared__ float aL[256];
  __shared__ int any;
  if (c == 0) any = 0;
  __syncthreads();
  int t0 = chunk * 256;
  float av = align[(size_t)b * TT_ + t0 + c];
  aL[c] = av;
  if (av != 0.f) any = 1;  // benign race
  __syncthreads();
  if (!any) return;
  const float* vp = value + ((size_t)b * TT_ + t0) * VD + c;
  float acc = 0.f;
  #pragma unroll 8
  for (int i = 0; i < 256; ++i) acc = fmaf(aL[i], vp[(size_t)i * VD], acc);
  atomicAdd(&u[b * VD + c], acc);
}

// ---------------- Kernel 5: context = u @ Wv + suma * bv ----------------
__global__ __launch_bounds__(128) void k_ctx(
    const float* __restrict__ u, const float* __restrict__ Wv,
    const float* __restrict__ bv, const float* __restrict__ suma,
    float* __restrict__ ctx) {
  int b = blockIdx.x, d = threadIdx.x;
  __shared__ float uL[VD];
  uL[d] = u[b * VD + d];
  uL[d + 128] = u[b * VD + d + 128];
  __syncthreads();
  float acc = suma[b] * bv[d];
  #pragma unroll 8
  for (int c = 0; c < VD; ++c) acc = fmaf(uL[c], Wv[c * DD + d], acc);
  ctx[b * DD + d] = acc;
}

extern "C" void kernel_launch(void* const* d_in, const int* in_sizes, int n_in,
                              void* d_out, int out_size, void* d_ws, size_t ws_size,
                              hipStream_t stream) {
  const float* query = (const float*)d_in[0];
  const float* value = (const float*)d_in[1];
  const float* prev  = (const float*)d_in[2];
  const float* Wq    = (const float*)d_in[3];
  const float* bq    = (const float*)d_in[4];
  const float* Wv    = (const float*)d_in[5];
  const float* bv    = (const float*)d_in[6];
  const float* attv  = (const float*)d_in[7];
  const float* sbias = (const float*)d_in[8];

  float* ctx_out   = (float*)d_out;                 // [32][128]
  float* align_out = (float*)d_out + BB * DD;       // [32][8192]

  float* ws = (float*)d_ws;
  float* q      = ws;                 // 4096
  float* score  = ws + 4096;          // 262144
  float* suma   = ws + 266240;        // 32
  float* carryL = ws + 266272;        // 32
  float* carryD = ws + 266304;        // 32
  int*   flags  = (int*)(ws + 266336);// 32
  float* u      = ws + 266368;        // 8192

  hipMemsetAsync(u, 0, BB * VD * sizeof(float), stream);

  k_qproj<<<BB, 128, 0, stream>>>(query, Wq, bq, q);

  // speculative scores for t < TSPEC
  k_score<<<dim3(TSPEC_TILES, BB), 256, 0, stream>>>(
      value, Wv, bv, q, attv, sbias, score, 0, nullptr);

  // scan phase 0 over t < TSPEC; decides fast path vs fallback per b
  k_scan<<<BB, 256, 0, stream>>>(score, prev, align_out, suma,
                                 carryL, carryD, flags, 0, TSPEC_CHUNKS, 0);

  // fallback scores for t >= TSPEC (early-exits per b when flags[b]==0)
  k_score<<<dim3(TT_ / TTILE - TSPEC_TILES, BB), 256, 0, stream>>>(
      value, Wv, bv, q, attv, sbias, score, TSPEC_TILES, flags);

  // scan continuation (early-exits when flags[b]==0)
  k_scan<<<BB, 256, 0, stream>>>(score, prev, align_out, suma,
                                 carryL, carryD, flags, TSPEC_CHUNKS,
                                 TT_ / 256 - TSPEC_CHUNKS, 1);

  k_u<<<dim3(TT_ / 256, BB), 256, 0, stream>>>(value, align_out, u);

  k_ctx<<<BB, 128, 0, stream>>>(u, Wv, bv, suma, ctx_out);
}